// Round 3
// baseline (37542.221 us; speedup 1.0000x reference)
//
#include <hip/hip_runtime.h>
#include <hip/hip_bf16.h>

#define SEQ 8192
#define HID 2048
#define NBLK 64        // persistent scan blocks (distinct CUs -> co-resident)
#define ROWS 32        // Wh rows per block (NBLK*ROWS == HID)
#define DEPTH 4        // poll pipeline depth (LDS-DMA slots per wave)

typedef short short8 __attribute__((ext_vector_type(8)));
typedef float floatx4 __attribute__((ext_vector_type(4)));
typedef unsigned uintx4 __attribute__((ext_vector_type(4)));

typedef const __attribute__((address_space(1))) void* gas_ptr;
typedef __attribute__((address_space(3))) void* las_ptr;

// Split 8 consecutive f32 into bf16 hi + bf16 lo fragments (RNE rounding).
__device__ __forceinline__ void split_bf16(const float* __restrict__ p,
                                           short8& hi, short8& lo) {
    const float4 f0 = *(const float4*)p;
    const float4 f1 = *(const float4*)(p + 4);
    const float f[8] = {f0.x, f0.y, f0.z, f0.w, f1.x, f1.y, f1.z, f1.w};
#pragma unroll
    for (int e = 0; e < 8; ++e) {
        const unsigned u = __float_as_uint(f[e]);
        const unsigned r = (u + 0x7fffu + ((u >> 16) & 1u)) & 0xffff0000u;
        hi[e] = (short)(r >> 16);
        const float l = f[e] - __uint_as_float(r);
        const unsigned ul = __float_as_uint(l);
        lo[e] = (short)((ul + 0x7fffu + ((ul >> 16) & 1u)) >> 16);
    }
}

// ---------------------------------------------------------------------------
// Kernel 1: xp[s,h] = sum_k x[s,k]*Wi[h,k] + bi[h]  (f32 in/out, bf16-split
// MFMA: 3 products per k-chunk, ~1e-4 abs error).
// ---------------------------------------------------------------------------
__global__ __launch_bounds__(256) void xproj_gemm(
    const float* __restrict__ x,       // [SEQ, HID]
    const float* __restrict__ Wi,      // [HID, HID]
    const float* __restrict__ bi,      // [HID]
    float* __restrict__ xp)            // [SEQ, HID]
{
    const int bn = blockIdx.x;
    const int bm = blockIdx.y;
    const int tid = threadIdx.x;
    const int wave = tid >> 6;
    const int lane = tid & 63;
    const int wM = wave & 1, wN = wave >> 1;
    const int l16 = lane & 15, kq = lane >> 4;
    const int m0 = bm * 64 + wM * 32;
    const int n0 = bn * 64 + wN * 32;

    floatx4 acc00 = {0.f,0.f,0.f,0.f}, acc01 = {0.f,0.f,0.f,0.f};
    floatx4 acc10 = {0.f,0.f,0.f,0.f}, acc11 = {0.f,0.f,0.f,0.f};

    const float* xA0 = x  + (size_t)(m0 + l16)      * HID;
    const float* xA1 = x  + (size_t)(m0 + 16 + l16) * HID;
    const float* wB0 = Wi + (size_t)(n0 + l16)      * HID;
    const float* wB1 = Wi + (size_t)(n0 + 16 + l16) * HID;

    for (int kc = 0; kc < HID; kc += 32) {
        const int k = kc + kq * 8;
        short8 a0h, a0l, a1h, a1l, b0h, b0l, b1h, b1l;
        split_bf16(xA0 + k, a0h, a0l);
        split_bf16(xA1 + k, a1h, a1l);
        split_bf16(wB0 + k, b0h, b0l);
        split_bf16(wB1 + k, b1h, b1l);
        acc00 = __builtin_amdgcn_mfma_f32_16x16x32_bf16(a0h, b0h, acc00, 0,0,0);
        acc00 = __builtin_amdgcn_mfma_f32_16x16x32_bf16(a0l, b0h, acc00, 0,0,0);
        acc00 = __builtin_amdgcn_mfma_f32_16x16x32_bf16(a0h, b0l, acc00, 0,0,0);
        acc01 = __builtin_amdgcn_mfma_f32_16x16x32_bf16(a0h, b1h, acc01, 0,0,0);
        acc01 = __builtin_amdgcn_mfma_f32_16x16x32_bf16(a0l, b1h, acc01, 0,0,0);
        acc01 = __builtin_amdgcn_mfma_f32_16x16x32_bf16(a0h, b1l, acc01, 0,0,0);
        acc10 = __builtin_amdgcn_mfma_f32_16x16x32_bf16(a1h, b0h, acc10, 0,0,0);
        acc10 = __builtin_amdgcn_mfma_f32_16x16x32_bf16(a1l, b0h, acc10, 0,0,0);
        acc10 = __builtin_amdgcn_mfma_f32_16x16x32_bf16(a1h, b0l, acc10, 0,0,0);
        acc11 = __builtin_amdgcn_mfma_f32_16x16x32_bf16(a1h, b1h, acc11, 0,0,0);
        acc11 = __builtin_amdgcn_mfma_f32_16x16x32_bf16(a1l, b1h, acc11, 0,0,0);
        acc11 = __builtin_amdgcn_mfma_f32_16x16x32_bf16(a1h, b1l, acc11, 0,0,0);
    }

    const float bi0 = bi[n0 + l16];
    const float bi1 = bi[n0 + 16 + l16];
#pragma unroll
    for (int reg = 0; reg < 4; ++reg) {
        const int mlo = m0 + kq * 4 + reg;
        const int mhi = mlo + 16;
        xp[(size_t)mlo * HID + n0 + l16]      = acc00[reg] + bi0;
        xp[(size_t)mlo * HID + n0 + 16 + l16] = acc01[reg] + bi1;
        xp[(size_t)mhi * HID + n0 + l16]      = acc10[reg] + bi0;
        xp[(size_t)mhi * HID + n0 + 16 + l16] = acc11[reg] + bi1;
    }
}

// ---------------------------------------------------------------------------
// Kernel 2: persistent recurrence, one-hop tagged-data exchange.
// Round-8 structure = round-5 protocol (u64 [tag:32|data:32] per row, verified)
// + DEPTH=4 pipelined polling via LDS-destination DMA (global_load_lds):
//  - round-7 post-mortem: register-destination pipelined polls are UNSOUND in
//    HIP source (compiler copies/spills in-flight asm load dests across loop
//    back-edges; no scoreboard). Fix: in-flight poll batches have NO dest
//    VGPR -- global_load_lds writes LDS. In-flight DMA legally crosses C
//    code, back-edges, and barriers.
//  - per wave, slot s = 2 DMA ops (dwordx4/lane): this wave's 2KB slice of
//    the 16KB parity buffer lands linearly in scr[wv][s][0..255] (tag+data).
//  - check/stage in plain C after "s_waitcnt vmcnt(6)": conservative-correct
//    by construction -- the 6 newest vm ops are always the other 3 slots'
//    issues, so <=6 outstanding => checked slot landed, independent of any
//    compiler-scheduled loads/stores (they are all older than the 6 newest).
//  - wave-uniform exit via __all (no divergent breaks); slot index uniform.
//  - slot 0 pre-issued at the previous step's tail (no registers -> safe);
//    sampling period ~RTT/DEPTH vs round-5's ~RTT. FETCH/step (rounds x
//    16KB) is the round-count diagnostic: round-5 showed ~4.4 rounds/step.
//  - coherence backstop: if DMA aux (SC0|SC1 = 17) fails to bypass L2, the
//    LDS image never freshens; after 64 spins fall back to the verified
//    round-5 register poll (correct, slow) -> no deadlock, visible in dur.
//  - LDS-only barrier (lgkmcnt(0); s_barrier): stores + DMA stay in flight.
// Safety: tag chain orders everything (round-5 argument): every block's waves
// collectively poll ALL rows each step; a wave's step-t hbuf store data-
// depends on its step-t LDS reads, so detecting all tag-(t-1) stores implies
// all waves' step-(t-1) h_lds reads completed before any step-t h_lds write.
// Buffer-parity reuse: tag t overwrites t-2 only after all blocks stored t-1.
// Late-landing leftover DMA writes scr slots that are re-issued and re-waited
// (vmcnt retires in order) before any read. ws poison 0xAAAAAAAA != any tag.
// ---------------------------------------------------------------------------
__global__ __launch_bounds__(512, 1) void rnn_scan(
    const float* __restrict__ Wh,    // [HID, HID]
    const float* __restrict__ bh,    // [HID]
    const float* __restrict__ xp,    // [SEQ, HID]
    unsigned long long* hbuf,        // [2][HID] tagged exchange
    float* out)                      // [SEQ*HID + HID]
{
    __shared__ float h_lds[HID];                                   // 8 KB
    __shared__ __align__(16) unsigned long long scr[8][DEPTH][256]; // 64 KB

    const int b   = blockIdx.x;
    const int tid = threadIdx.x;
    const int wv  = tid >> 6;        // wave = row group (4 rows each)
    const int L   = tid & 63;
    const int row = b * ROWS + wv * 4 + L;   // meaningful when L < 4

    // one-time: Wh rows -> registers. Lane L covers cols 256*j+4*L+{0..3}.
    floatx4 w[4][8];
#pragma unroll
    for (int r = 0; r < 4; ++r) {
        const size_t rr = (size_t)(b * ROWS + wv * 4 + r);
#pragma unroll
        for (int j = 0; j < 8; ++j)
            w[r][j] = *(const floatx4*)(Wh + rr * HID + 256 * j + 4 * L);
    }
    const float bh_l = (L < 4) ? bh[row] : 0.f;

    float xp_cur = (L < 4) ? xp[row] : 0.f;   // step 0
    float prev_h = 0.f;

    // issue one poll batch: wave wv's 2KB slice (rows 128wv.. / 1024+128wv..)
    // of parity buffer at gbase; lands linearly in scr[wv][slot][*].
    auto issue = [&](const char* gbase, int slot) {
        __builtin_amdgcn_global_load_lds(
            (gas_ptr)(const void*)(gbase + 16 * L),
            (las_ptr)(void*)&scr[wv][slot][0], 16, 0, 17);
        __builtin_amdgcn_global_load_lds(
            (gas_ptr)(const void*)(gbase + 8192 + 16 * L),
            (las_ptr)(void*)&scr[wv][slot][128], 16, 0, 17);
    };

    for (int t = 0; t < SEQ; ++t) {
        float acc[4] = {0.f, 0.f, 0.f, 0.f};

        if (t > 0) {
            const unsigned want = (unsigned)(t - 1);
            const char* g = (const char*)(hbuf + ((t - 1) & 1) * HID) + 1024 * wv;
            // slot 0 was pre-issued at the previous tail; fill the pipeline
            issue(g, 1); issue(g, 2); issue(g, 3);
            int slot = 0, spins = 0;
            for (;;) {
                asm volatile("s_waitcnt vmcnt(6)" ::: "memory");
                const unsigned long long v0 = scr[wv][slot][L];
                const unsigned long long v1 = scr[wv][slot][64 + L];
                const unsigned long long v2 = scr[wv][slot][128 + L];
                const unsigned long long v3 = scr[wv][slot][192 + L];
                const bool ok = ((unsigned)(v0 >> 32) == want) &
                                ((unsigned)(v1 >> 32) == want) &
                                ((unsigned)(v2 >> 32) == want) &
                                ((unsigned)(v3 >> 32) == want);
                if (__all(ok)) {
                    h_lds[128 * wv + L]             = __uint_as_float((unsigned)v0);
                    h_lds[128 * wv + 64 + L]        = __uint_as_float((unsigned)v1);
                    h_lds[1024 + 128 * wv + L]      = __uint_as_float((unsigned)v2);
                    h_lds[1024 + 128 * wv + 64 + L] = __uint_as_float((unsigned)v3);
                    break;
                }
                if (++spins > 64) {
                    // backstop: verified round-5 register poll (sc0 sc1,
                    // issue+wait+consume inside one asm statement => sound)
                    const unsigned long long* src = hbuf + ((t - 1) & 1) * HID;
                    const unsigned long long* s0 = src + 2 * tid;
                    const unsigned long long* s1 = src + 1024 + 2 * tid;
                    uintx4 p0, p1;
                    do {
                        asm volatile(
                            "global_load_dwordx4 %0, %2, off sc0 sc1\n\t"
                            "global_load_dwordx4 %1, %3, off sc0 sc1\n\t"
                            "s_waitcnt vmcnt(0)"
                            : "=&v"(p0), "=&v"(p1)
                            : "v"(s0), "v"(s1)
                            : "memory");
                    } while ((p0[1] != want) | (p0[3] != want) |
                             (p1[1] != want) | (p1[3] != want));
                    *(float2*)&h_lds[2 * tid] = make_float2(
                        __uint_as_float(p0[0]), __uint_as_float(p0[2]));
                    *(float2*)&h_lds[1024 + 2 * tid] = make_float2(
                        __uint_as_float(p1[0]), __uint_as_float(p1[2]));
                    break;
                }
                issue(g, slot);                 // recycle this slot
                slot = (slot + 1) & (DEPTH - 1);
            }
            // deferred out[] store for step t-1: retires under compute
            if (L < 4) out[(size_t)(t - 1) * HID + row] = prev_h;
            // LDS-only barrier: do NOT drain vmcnt (stores + DMA in flight)
            asm volatile("s_waitcnt lgkmcnt(0)\n\ts_barrier" ::: "memory");
        }

        // prefetch next step's xp (used next iteration; fully hidden)
        float xp_next = 0.f;
        if (L < 4 && t + 1 < SEQ) xp_next = xp[(size_t)(t + 1) * HID + row];

        if (t > 0) {
            // dot: 4 rows x 32 cols per lane (b128 LDS reads, conflict-free)
#pragma unroll
            for (int j = 0; j < 8; ++j) {
                const float4 hv = *(const float4*)&h_lds[256 * j + 4 * L];
#pragma unroll
                for (int r = 0; r < 4; ++r) {
                    acc[r] += w[r][j][0] * hv.x;
                    acc[r] += w[r][j][1] * hv.y;
                    acc[r] += w[r][j][2] * hv.z;
                    acc[r] += w[r][j][3] * hv.w;
                }
            }
        }

        // 64-lane butterfly reduce
#pragma unroll
        for (int off = 32; off > 0; off >>= 1) {
#pragma unroll
            for (int r = 0; r < 4; ++r) acc[r] += __shfl_xor(acc[r], off, 64);
        }

        if (L < 4) {
            float a = acc[L] + xp_cur + bh_l;
            a = fminf(fmaxf(a, -15.f), 15.f);
            const float e = __expf(2.f * a);
            prev_h = (e - 1.f) / (e + 1.f);
        }

        // tail: pre-issue next step's slot 0 (LDS-dest DMA, hazard-free),
        // then the tagged store
        if (t + 1 < SEQ) {
            const char* gn = (const char*)(hbuf + (t & 1) * HID) + 1024 * wv;
            issue(gn, 0);
        }
        if (L < 4) {
            const unsigned long long tagged =
                ((unsigned long long)(unsigned)t << 32) |
                (unsigned long long)__float_as_uint(prev_h);
            __hip_atomic_store(&hbuf[(t & 1) * HID + row], tagged,
                               __ATOMIC_RELAXED, __HIP_MEMORY_SCOPE_AGENT);
        }
        xp_cur = xp_next;
    }

    if (L < 4) {
        out[(size_t)(SEQ - 1) * HID + row] = prev_h;   // last step's output
        out[(size_t)SEQ * HID + row]       = prev_h;   // h_n
    }
}

// ---------------------------------------------------------------------------
extern "C" void kernel_launch(void* const* d_in, const int* in_sizes, int n_in,
                              void* d_out, int out_size, void* d_ws, size_t ws_size,
                              hipStream_t stream) {
    const float* x  = (const float*)d_in[0];   // [8192,2048] f32
    const float* Wi = (const float*)d_in[1];   // [2048,2048] f32
    const float* bi = (const float*)d_in[2];   // [2048] f32
    const float* Wh = (const float*)d_in[3];   // [2048,2048] f32
    const float* bh = (const float*)d_in[4];   // [2048] f32
    float* out      = (float*)d_out;           // outputs ++ h_n

    // ws: xp f32 [SEQ*HID] (64 MB) | hbuf u64 [2*HID] (32 KB)
    float* xp = (float*)d_ws;
    unsigned long long* hbuf = (unsigned long long*)(xp + (size_t)SEQ * HID);

    xproj_gemm<<<dim3(HID / 64, SEQ / 64), 256, 0, stream>>>(x, Wi, bi, xp);
    rnn_scan<<<NBLK, 512, 0, stream>>>(Wh, bh, xp, hbuf, out);
}

// Round 4
// 23761.124 us; speedup vs baseline: 1.5800x; 1.5800x over previous
//
#include <hip/hip_runtime.h>
#include <hip/hip_bf16.h>

#define SEQ 8192
#define HID 2048
#define NBLK 64        // persistent scan blocks (distinct CUs -> co-resident)
#define ROWS 32        // Wh rows per block (NBLK*ROWS == HID)

typedef short short8 __attribute__((ext_vector_type(8)));
typedef float floatx4 __attribute__((ext_vector_type(4)));
typedef unsigned uintx4 __attribute__((ext_vector_type(4)));

// Split 8 consecutive f32 into bf16 hi + bf16 lo fragments (RNE rounding).
__device__ __forceinline__ void split_bf16(const float* __restrict__ p,
                                           short8& hi, short8& lo) {
    const float4 f0 = *(const float4*)p;
    const float4 f1 = *(const float4*)(p + 4);
    const float f[8] = {f0.x, f0.y, f0.z, f0.w, f1.x, f1.y, f1.z, f1.w};
#pragma unroll
    for (int e = 0; e < 8; ++e) {
        const unsigned u = __float_as_uint(f[e]);
        const unsigned r = (u + 0x7fffu + ((u >> 16) & 1u)) & 0xffff0000u;
        hi[e] = (short)(r >> 16);
        const float l = f[e] - __uint_as_float(r);
        const unsigned ul = __float_as_uint(l);
        lo[e] = (short)((ul + 0x7fffu + ((ul >> 16) & 1u)) >> 16);
    }
}

// ---------------------------------------------------------------------------
// Kernel 1: xp[s,h] = sum_k x[s,k]*Wi[h,k] + bi[h]  (f32 in/out, bf16-split
// MFMA: 3 products per k-chunk, ~1e-4 abs error).
// ---------------------------------------------------------------------------
__global__ __launch_bounds__(256) void xproj_gemm(
    const float* __restrict__ x,       // [SEQ, HID]
    const float* __restrict__ Wi,      // [HID, HID]
    const float* __restrict__ bi,      // [HID]
    float* __restrict__ xp)            // [SEQ, HID]
{
    const int bn = blockIdx.x;
    const int bm = blockIdx.y;
    const int tid = threadIdx.x;
    const int wave = tid >> 6;
    const int lane = tid & 63;
    const int wM = wave & 1, wN = wave >> 1;
    const int l16 = lane & 15, kq = lane >> 4;
    const int m0 = bm * 64 + wM * 32;
    const int n0 = bn * 64 + wN * 32;

    floatx4 acc00 = {0.f,0.f,0.f,0.f}, acc01 = {0.f,0.f,0.f,0.f};
    floatx4 acc10 = {0.f,0.f,0.f,0.f}, acc11 = {0.f,0.f,0.f,0.f};

    const float* xA0 = x  + (size_t)(m0 + l16)      * HID;
    const float* xA1 = x  + (size_t)(m0 + 16 + l16) * HID;
    const float* wB0 = Wi + (size_t)(n0 + l16)      * HID;
    const float* wB1 = Wi + (size_t)(n0 + 16 + l16) * HID;

    for (int kc = 0; kc < HID; kc += 32) {
        const int k = kc + kq * 8;
        short8 a0h, a0l, a1h, a1l, b0h, b0l, b1h, b1l;
        split_bf16(xA0 + k, a0h, a0l);
        split_bf16(xA1 + k, a1h, a1l);
        split_bf16(wB0 + k, b0h, b0l);
        split_bf16(wB1 + k, b1h, b1l);
        acc00 = __builtin_amdgcn_mfma_f32_16x16x32_bf16(a0h, b0h, acc00, 0,0,0);
        acc00 = __builtin_amdgcn_mfma_f32_16x16x32_bf16(a0l, b0h, acc00, 0,0,0);
        acc00 = __builtin_amdgcn_mfma_f32_16x16x32_bf16(a0h, b0l, acc00, 0,0,0);
        acc01 = __builtin_amdgcn_mfma_f32_16x16x32_bf16(a0h, b1h, acc01, 0,0,0);
        acc01 = __builtin_amdgcn_mfma_f32_16x16x32_bf16(a0l, b1h, acc01, 0,0,0);
        acc01 = __builtin_amdgcn_mfma_f32_16x16x32_bf16(a0h, b1l, acc01, 0,0,0);
        acc10 = __builtin_amdgcn_mfma_f32_16x16x32_bf16(a1h, b0h, acc10, 0,0,0);
        acc10 = __builtin_amdgcn_mfma_f32_16x16x32_bf16(a1l, b0h, acc10, 0,0,0);
        acc10 = __builtin_amdgcn_mfma_f32_16x16x32_bf16(a1h, b0l, acc10, 0,0,0);
        acc11 = __builtin_amdgcn_mfma_f32_16x16x32_bf16(a1h, b1h, acc11, 0,0,0);
        acc11 = __builtin_amdgcn_mfma_f32_16x16x32_bf16(a1l, b1h, acc11, 0,0,0);
        acc11 = __builtin_amdgcn_mfma_f32_16x16x32_bf16(a1h, b1l, acc11, 0,0,0);
    }

    const float bi0 = bi[n0 + l16];
    const float bi1 = bi[n0 + 16 + l16];
#pragma unroll
    for (int reg = 0; reg < 4; ++reg) {
        const int mlo = m0 + kq * 4 + reg;
        const int mhi = mlo + 16;
        xp[(size_t)mlo * HID + n0 + l16]      = acc00[reg] + bi0;
        xp[(size_t)mlo * HID + n0 + 16 + l16] = acc01[reg] + bi1;
        xp[(size_t)mhi * HID + n0 + l16]      = acc10[reg] + bi0;
        xp[(size_t)mhi * HID + n0 + 16 + l16] = acc11[reg] + bi1;
    }
}

// ---------------------------------------------------------------------------
// Kernel 2: persistent recurrence, hierarchical tagged exchange.
// Round-9 = round-5 protocol (verified 19.6ms) + XCD-local mirror relay:
//  - ELECTION (placement-assumption-free): each block reads HW_REG_XCC_ID
//    [m09] and atomicMin's claim[xcd] with its blockIdx. ws poison
//    0xAAAAAAAA > any blockIdx, so no init needed. Blocks that saw
//    old > b self-select as relays (>=1 per occupied XCD; duplicates
//    benign -- identical tagged 8B-atomic forwards).
//  - RELAYS poll global hbuf exactly like round-5 (sc0 sc1, single-asm
//    vmcnt(0), per-thread exit) and per-thread FORWARD each detected 32B
//    chunk to mirror[xcd] with sc0-only stores: the line stays DIRTY in
//    the relay's own XCD L2 (no sc1 => no LLC writethrough).
//  - CONSUMERS poll mirror[own xcd] with sc0-only loads: L2-hit RTT
//    (~250cy) vs global ~1.2kcy => 4-5x shorter sampling period; also
//    collapses next-step producer-store spread (tighter lockstep). Every
//    4th miss: round-5 global poll as liveness fallback (tags gate
//    correctness either way; mirror lag can never false-match).
//  - global LLC poll pressure drops ~4-8x (only relays poll hbuf).
// Safety: unchanged round-5 tag-chain argument. All blocks poll ALL 2048
// rows (relay: global; consumer: mirror image of same tagged data). A
// block's tag-t store data-depends on its step-t LDS reads; any tag-t+1
// store transitively requires every block's tag-t store; so parity slot
// overwrite (t+1 over t-1, in hbuf AND mirror) cannot precede any block's
// reads of t-1. 8B stores are atomic; dwordx4 loads can't tear a u64.
// Poison tag 0x1555/0xAAAA.. never matches want in [0, SEQ).
// ---------------------------------------------------------------------------
__global__ __launch_bounds__(512, 1) void rnn_scan(
    const float* __restrict__ Wh,    // [HID, HID]
    const float* __restrict__ bh,    // [HID]
    const float* __restrict__ xp,    // [SEQ, HID]
    unsigned long long* hbuf,        // [2][HID] global tagged exchange
    unsigned long long* mirror,      // [8][2][HID] per-XCD L2 mirrors
    unsigned* claim,                 // [8] relay election (poisoned)
    float* out)                      // [SEQ*HID + HID]
{
    __shared__ float h_lds[HID];
    __shared__ unsigned meta[2];     // [0]=xcd, [1]=is_relay

    const int b   = blockIdx.x;
    const int tid = threadIdx.x;
    const int wv  = tid >> 6;        // wave = row group (4 rows each)
    const int L   = tid & 63;
    const int row = b * ROWS + wv * 4 + L;   // meaningful when L < 4

    // ---- relay election (once) ----
    if (tid == 0) {
        unsigned x;
        asm volatile("s_getreg_b32 %0, hwreg(HW_REG_XCC_ID)" : "=s"(x));
        x &= 7;
        const unsigned old = __hip_atomic_fetch_min(
            &claim[x], (unsigned)b, __ATOMIC_RELAXED,
            __HIP_MEMORY_SCOPE_AGENT);
        meta[0] = x;
        meta[1] = (old > (unsigned)b) ? 1u : 0u;
    }
    __syncthreads();
    const unsigned xcd = meta[0];
    const bool is_relay = (meta[1] != 0);

    // one-time: Wh rows -> registers. Lane L covers cols 256*j+4*L+{0..3}.
    floatx4 w[4][8];
#pragma unroll
    for (int r = 0; r < 4; ++r) {
        const size_t rr = (size_t)(b * ROWS + wv * 4 + r);
#pragma unroll
        for (int j = 0; j < 8; ++j)
            w[r][j] = *(const floatx4*)(Wh + rr * HID + 256 * j + 4 * L);
    }
    const float bh_l = (L < 4) ? bh[row] : 0.f;

    float xp_cur = (L < 4) ? xp[row] : 0.f;   // step 0
    float prev_h = 0.f;

    for (int t = 0; t < SEQ; ++t) {
        float acc[4] = {0.f, 0.f, 0.f, 0.f};

        if (t > 0) {
            const int par = (t - 1) & 1;
            const unsigned want = (unsigned)(t - 1);
            const unsigned long long* src = hbuf + (size_t)par * HID;
            const unsigned long long* s0 = src + 2 * tid;
            const unsigned long long* s1 = src + 1024 + 2 * tid;
            uintx4 p0, p1;   // [data, tag, data, tag]

            if (is_relay) {
                // round-5 global poll (sound: issue+wait+consume in one asm)
                do {
                    asm volatile(
                        "global_load_dwordx4 %0, %2, off sc0 sc1\n\t"
                        "global_load_dwordx4 %1, %3, off sc0 sc1\n\t"
                        "s_waitcnt vmcnt(0)"
                        : "=&v"(p0), "=&v"(p1)
                        : "v"(s0), "v"(s1)
                        : "memory");
                } while ((p0[1] != want) | (p0[3] != want) |
                         (p1[1] != want) | (p1[3] != want));
                // forward to own-XCD mirror: 4 x 8B stores, sc0 only
                // (L2-resident dirty; fire-and-forget, drained by next poll)
                unsigned long long* m =
                    mirror + ((size_t)xcd * 2 + par) * HID;
                const unsigned long long v0 =
                    ((unsigned long long)p0[1] << 32) | p0[0];
                const unsigned long long v1 =
                    ((unsigned long long)p0[3] << 32) | p0[2];
                const unsigned long long v2 =
                    ((unsigned long long)p1[1] << 32) | p1[0];
                const unsigned long long v3 =
                    ((unsigned long long)p1[3] << 32) | p1[2];
                asm volatile(
                    "global_store_dwordx2 %0, %4, off sc0\n\t"
                    "global_store_dwordx2 %1, %5, off sc0\n\t"
                    "global_store_dwordx2 %2, %6, off sc0\n\t"
                    "global_store_dwordx2 %3, %7, off sc0"
                    :: "v"(m + 2 * tid), "v"(m + 2 * tid + 1),
                       "v"(m + 1024 + 2 * tid), "v"(m + 1024 + 2 * tid + 1),
                       "v"(v0), "v"(v1), "v"(v2), "v"(v3)
                    : "memory");
            } else {
                // consumer: fast local-L2 mirror poll (sc0 only), with
                // 1-in-4 global fallback for liveness
                const unsigned long long* msrc =
                    mirror + ((size_t)xcd * 2 + par) * HID;
                const unsigned long long* m0 = msrc + 2 * tid;
                const unsigned long long* m1 = msrc + 1024 + 2 * tid;
                unsigned spin = 0;
                for (;;) {
                    asm volatile(
                        "global_load_dwordx4 %0, %2, off sc0\n\t"
                        "global_load_dwordx4 %1, %3, off sc0\n\t"
                        "s_waitcnt vmcnt(0)"
                        : "=&v"(p0), "=&v"(p1)
                        : "v"(m0), "v"(m1)
                        : "memory");
                    if ((p0[1] == want) & (p0[3] == want) &
                        (p1[1] == want) & (p1[3] == want)) break;
                    if ((++spin & 3) == 0) {
                        asm volatile(
                            "global_load_dwordx4 %0, %2, off sc0 sc1\n\t"
                            "global_load_dwordx4 %1, %3, off sc0 sc1\n\t"
                            "s_waitcnt vmcnt(0)"
                            : "=&v"(p0), "=&v"(p1)
                            : "v"(s0), "v"(s1)
                            : "memory");
                        if ((p0[1] == want) & (p0[3] == want) &
                            (p1[1] == want) & (p1[3] == want)) break;
                    }
                }
            }

            // stage data dwords -> h_lds (round-5 mapping)
            *(float2*)&h_lds[2 * tid] =
                make_float2(__uint_as_float(p0[0]), __uint_as_float(p0[2]));
            *(float2*)&h_lds[1024 + 2 * tid] =
                make_float2(__uint_as_float(p1[0]), __uint_as_float(p1[2]));
            // deferred out[] store for step t-1: retires under compute
            if (L < 4) out[(size_t)(t - 1) * HID + row] = prev_h;
            // LDS-only barrier: do NOT drain vmcnt (stores stay in flight)
            asm volatile("s_waitcnt lgkmcnt(0)\n\ts_barrier" ::: "memory");
        }

        // prefetch next step's xp (used next iteration; fully hidden)
        float xp_next = 0.f;
        if (L < 4 && t + 1 < SEQ) xp_next = xp[(size_t)(t + 1) * HID + row];

        if (t > 0) {
            // dot: 4 rows x 32 cols per lane (b128 LDS reads, conflict-free)
#pragma unroll
            for (int j = 0; j < 8; ++j) {
                const float4 hv = *(const float4*)&h_lds[256 * j + 4 * L];
#pragma unroll
                for (int r = 0; r < 4; ++r) {
                    acc[r] += w[r][j][0] * hv.x;
                    acc[r] += w[r][j][1] * hv.y;
                    acc[r] += w[r][j][2] * hv.z;
                    acc[r] += w[r][j][3] * hv.w;
                }
            }
        }

        // 64-lane butterfly reduce
#pragma unroll
        for (int off = 32; off > 0; off >>= 1) {
#pragma unroll
            for (int r = 0; r < 4; ++r) acc[r] += __shfl_xor(acc[r], off, 64);
        }

        if (L < 4) {
            float a = acc[L] + xp_cur + bh_l;
            a = fminf(fmaxf(a, -15.f), 15.f);
            const float e = __expf(2.f * a);
            const float hval = (e - 1.f) / (e + 1.f);
            const unsigned long long tagged =
                ((unsigned long long)(unsigned)t << 32) |
                (unsigned long long)__float_as_uint(hval);
            __hip_atomic_store(&hbuf[(t & 1) * HID + row], tagged,
                               __ATOMIC_RELAXED, __HIP_MEMORY_SCOPE_AGENT);
            prev_h = hval;
        }
        xp_cur = xp_next;
    }

    if (L < 4) {
        out[(size_t)(SEQ - 1) * HID + row] = prev_h;   // last step's output
        out[(size_t)SEQ * HID + row]       = prev_h;   // h_n
    }
}

// ---------------------------------------------------------------------------
extern "C" void kernel_launch(void* const* d_in, const int* in_sizes, int n_in,
                              void* d_out, int out_size, void* d_ws, size_t ws_size,
                              hipStream_t stream) {
    const float* x  = (const float*)d_in[0];   // [8192,2048] f32
    const float* Wi = (const float*)d_in[1];   // [2048,2048] f32
    const float* bi = (const float*)d_in[2];   // [2048] f32
    const float* Wh = (const float*)d_in[3];   // [2048,2048] f32
    const float* bh = (const float*)d_in[4];   // [2048] f32
    float* out      = (float*)d_out;           // outputs ++ h_n

    // ws: xp f32 [SEQ*HID] (64MB) | hbuf u64 [2*HID] (32KB)
    //   | mirror u64 [8][2][HID] (256KB) | claim u32 [8]
    float* xp = (float*)d_ws;
    unsigned long long* hbuf = (unsigned long long*)(xp + (size_t)SEQ * HID);
    unsigned long long* mirror = hbuf + 2 * HID;
    unsigned* claim = (unsigned*)(mirror + 8 * 2 * HID);

    xproj_gemm<<<dim3(HID / 64, SEQ / 64), 256, 0, stream>>>(x, Wi, bi, xp);
    rnn_scan<<<NBLK, 512, 0, stream>>>(Wh, bh, xp, hbuf, mirror, claim, out);
}

// Round 6
// 21275.107 us; speedup vs baseline: 1.7646x; 1.1169x over previous
//
#include <hip/hip_runtime.h>
#include <hip/hip_bf16.h>

#define SEQ 8192
#define HID 2048
#define NBLK 64        // persistent scan blocks (distinct CUs -> co-resident)
#define ROWS 32        // Wh rows per block (NBLK*ROWS == HID)

typedef short short8 __attribute__((ext_vector_type(8)));
typedef float floatx4 __attribute__((ext_vector_type(4)));
typedef unsigned uintx4 __attribute__((ext_vector_type(4)));

// Split 8 consecutive f32 into bf16 hi + bf16 lo fragments (RNE rounding).
__device__ __forceinline__ void split_bf16(const float* __restrict__ p,
                                           short8& hi, short8& lo) {
    const float4 f0 = *(const float4*)p;
    const float4 f1 = *(const float4*)(p + 4);
    const float f[8] = {f0.x, f0.y, f0.z, f0.w, f1.x, f1.y, f1.z, f1.w};
#pragma unroll
    for (int e = 0; e < 8; ++e) {
        const unsigned u = __float_as_uint(f[e]);
        const unsigned r = (u + 0x7fffu + ((u >> 16) & 1u)) & 0xffff0000u;
        hi[e] = (short)(r >> 16);
        const float l = f[e] - __uint_as_float(r);
        const unsigned ul = __float_as_uint(l);
        lo[e] = (short)((ul + 0x7fffu + ((ul >> 16) & 1u)) >> 16);
    }
}

// ---------------------------------------------------------------------------
// Kernel 1: xp[s,h] = sum_k x[s,k]*Wi[h,k] + bi[h]  (f32 in/out, bf16-split
// MFMA: 3 products per k-chunk, ~1e-4 abs error).
// ---------------------------------------------------------------------------
__global__ __launch_bounds__(256) void xproj_gemm(
    const float* __restrict__ x,       // [SEQ, HID]
    const float* __restrict__ Wi,      // [HID, HID]
    const float* __restrict__ bi,      // [HID]
    float* __restrict__ xp)            // [SEQ, HID]
{
    const int bn = blockIdx.x;
    const int bm = blockIdx.y;
    const int tid = threadIdx.x;
    const int wave = tid >> 6;
    const int lane = tid & 63;
    const int wM = wave & 1, wN = wave >> 1;
    const int l16 = lane & 15, kq = lane >> 4;
    const int m0 = bm * 64 + wM * 32;
    const int n0 = bn * 64 + wN * 32;

    floatx4 acc00 = {0.f,0.f,0.f,0.f}, acc01 = {0.f,0.f,0.f,0.f};
    floatx4 acc10 = {0.f,0.f,0.f,0.f}, acc11 = {0.f,0.f,0.f,0.f};

    const float* xA0 = x  + (size_t)(m0 + l16)      * HID;
    const float* xA1 = x  + (size_t)(m0 + 16 + l16) * HID;
    const float* wB0 = Wi + (size_t)(n0 + l16)      * HID;
    const float* wB1 = Wi + (size_t)(n0 + 16 + l16) * HID;

    for (int kc = 0; kc < HID; kc += 32) {
        const int k = kc + kq * 8;
        short8 a0h, a0l, a1h, a1l, b0h, b0l, b1h, b1l;
        split_bf16(xA0 + k, a0h, a0l);
        split_bf16(xA1 + k, a1h, a1l);
        split_bf16(wB0 + k, b0h, b0l);
        split_bf16(wB1 + k, b1h, b1l);
        acc00 = __builtin_amdgcn_mfma_f32_16x16x32_bf16(a0h, b0h, acc00, 0,0,0);
        acc00 = __builtin_amdgcn_mfma_f32_16x16x32_bf16(a0l, b0h, acc00, 0,0,0);
        acc00 = __builtin_amdgcn_mfma_f32_16x16x32_bf16(a0h, b0l, acc00, 0,0,0);
        acc01 = __builtin_amdgcn_mfma_f32_16x16x32_bf16(a0h, b1h, acc01, 0,0,0);
        acc01 = __builtin_amdgcn_mfma_f32_16x16x32_bf16(a0l, b1h, acc01, 0,0,0);
        acc01 = __builtin_amdgcn_mfma_f32_16x16x32_bf16(a0h, b1l, acc01, 0,0,0);
        acc10 = __builtin_amdgcn_mfma_f32_16x16x32_bf16(a1h, b0h, acc10, 0,0,0);
        acc10 = __builtin_amdgcn_mfma_f32_16x16x32_bf16(a1l, b0h, acc10, 0,0,0);
        acc10 = __builtin_amdgcn_mfma_f32_16x16x32_bf16(a1h, b0l, acc10, 0,0,0);
        acc11 = __builtin_amdgcn_mfma_f32_16x16x32_bf16(a1h, b1h, acc11, 0,0,0);
        acc11 = __builtin_amdgcn_mfma_f32_16x16x32_bf16(a1l, b1h, acc11, 0,0,0);
        acc11 = __builtin_amdgcn_mfma_f32_16x16x32_bf16(a1h, b1l, acc11, 0,0,0);
    }

    const float bi0 = bi[n0 + l16];
    const float bi1 = bi[n0 + 16 + l16];
#pragma unroll
    for (int reg = 0; reg < 4; ++reg) {
        const int mlo = m0 + kq * 4 + reg;
        const int mhi = mlo + 16;
        xp[(size_t)mlo * HID + n0 + l16]      = acc00[reg] + bi0;
        xp[(size_t)mlo * HID + n0 + 16 + l16] = acc01[reg] + bi1;
        xp[(size_t)mhi * HID + n0 + l16]      = acc10[reg] + bi0;
        xp[(size_t)mhi * HID + n0 + 16 + l16] = acc11[reg] + bi1;
    }
}

// ---------------------------------------------------------------------------
// Kernel 2: persistent recurrence, one-hop tagged-data exchange.
// Round-11 = round-0/5 structure (verified 19.6ms; rounds 6-9 all regressed:
// packed exchange +5%, reg-pipelined poll unsound, LDS-DMA poll +86%, XCD
// relay +20% -- exchange latency is at its sc0sc1/DRAM structural floor)
// + VALU-pipe reduction:
//  - the old 64-lane butterfly was 24 __shfl_xor (DS ops) per wave = 192 DS
//    ops/block serialized through the CU's single LDS pipe (~5.8cy each),
//    stacked on the dot's 64 ds_read_b128 -- the compute phase was
//    ~1400-1800cy, not ~700.
//  - new reduce: per acc, 4x DPP row_ror rotate-accumulate (VALU pipe,
//    rocPRIM idiom; literal dpp_ctrl 0x121/2/4/8 -- the builtin requires an
//    ICE, round-10's "0x120|N" in an unrolled loop did not compile) collapses
//    each 16-lane row, then only 2 __shfl_xor levels (16,32) cross groups.
//    DS ops/wave: 24 -> 8.
//  - poll = 2x global_load_dwordx4 sc0 sc1 per thread (dense 1KB/wave/instr)
//  - LDS-only barrier (s_waitcnt lgkmcnt(0); s_barrier): global stores stay
//    in flight across the step boundary (no vmcnt(0) drain)
//  - out[] store for step t-1 issued at step t post-detect (fully hidden)
//  - xp prefetched one step ahead
// Safety: tag chain orders everything. A wave's step-t hbuf store data-
// depends on its step-t LDS reads; step-t+1 staging polls ALL slots (incl.
// own block's rows), so all waves' reads are complete before any LDS write.
// Buffer-parity reuse is safe: tag t overwrites tag t-2 only after every
// block stored t-1, which implies every block finished polling t-2.
// ws poison 0xAAAAAAAA never equals a tag in [0, SEQ).
// ---------------------------------------------------------------------------

// one DPP row_ror rotate-accumulate level (ctrl must be a literal ICE)
#define DPP_ROR_ACC(v, ctrl)                                              \
    v += __int_as_float(__builtin_amdgcn_update_dpp(                      \
        __float_as_int(v), __float_as_int(v), (ctrl), 0xf, 0xf, false))

__global__ __launch_bounds__(512, 1) void rnn_scan(
    const float* __restrict__ Wh,    // [HID, HID]
    const float* __restrict__ bh,    // [HID]
    const float* __restrict__ xp,    // [SEQ, HID]
    unsigned long long* hbuf,        // [2][HID] tagged exchange
    float* out)                      // [SEQ*HID + HID]
{
    __shared__ float h_lds[HID];

    const int b   = blockIdx.x;
    const int tid = threadIdx.x;
    const int wv  = tid >> 6;        // wave = row group (4 rows each)
    const int L   = tid & 63;
    const int row = b * ROWS + wv * 4 + L;   // meaningful when L < 4

    // one-time: Wh rows -> registers. Lane L covers cols 256*j+4*L+{0..3}.
    floatx4 w[4][8];
#pragma unroll
    for (int r = 0; r < 4; ++r) {
        const size_t rr = (size_t)(b * ROWS + wv * 4 + r);
#pragma unroll
        for (int j = 0; j < 8; ++j)
            w[r][j] = *(const floatx4*)(Wh + rr * HID + 256 * j + 4 * L);
    }
    const float bh_l = (L < 4) ? bh[row] : 0.f;

    float xp_cur = (L < 4) ? xp[row] : 0.f;   // step 0
    float prev_h = 0.f;

    for (int t = 0; t < SEQ; ++t) {
        float acc[4] = {0.f, 0.f, 0.f, 0.f};

        if (t > 0) {
            const unsigned long long* src = hbuf + ((t - 1) & 1) * HID;
            const unsigned want = (unsigned)(t - 1);
            const unsigned long long* s0 = src + 2 * tid;
            const unsigned long long* s1 = src + 1024 + 2 * tid;
            uintx4 p0, p1;   // [data, tag, data, tag]
            do {   // one round-trip per retry round; wide + coalesced
                asm volatile(
                    "global_load_dwordx4 %0, %2, off sc0 sc1\n\t"
                    "global_load_dwordx4 %1, %3, off sc0 sc1\n\t"
                    "s_waitcnt vmcnt(0)"
                    : "=&v"(p0), "=&v"(p1)
                    : "v"(s0), "v"(s1)
                    : "memory");
            } while ((p0[1] != want) | (p0[3] != want) |
                     (p1[1] != want) | (p1[3] != want));
            *(float2*)&h_lds[2 * tid] =
                make_float2(__uint_as_float(p0[0]), __uint_as_float(p0[2]));
            *(float2*)&h_lds[1024 + 2 * tid] =
                make_float2(__uint_as_float(p1[0]), __uint_as_float(p1[2]));
            // deferred out[] store for step t-1: ~1800cy to retire unseen
            if (L < 4) out[(size_t)(t - 1) * HID + row] = prev_h;
            // LDS-only barrier: do NOT drain vmcnt (stores stay in flight)
            asm volatile("s_waitcnt lgkmcnt(0)\n\ts_barrier" ::: "memory");
        }

        // prefetch next step's xp (used next iteration; fully hidden)
        float xp_next = 0.f;
        if (L < 4 && t + 1 < SEQ) xp_next = xp[(size_t)(t + 1) * HID + row];

        if (t > 0) {
            // dot: 4 rows x 32 cols per lane (b128 LDS reads, conflict-free)
#pragma unroll
            for (int j = 0; j < 8; ++j) {
                const float4 hv = *(const float4*)&h_lds[256 * j + 4 * L];
#pragma unroll
                for (int r = 0; r < 4; ++r) {
                    acc[r] += w[r][j][0] * hv.x;
                    acc[r] += w[r][j][1] * hv.y;
                    acc[r] += w[r][j][2] * hv.z;
                    acc[r] += w[r][j][3] * hv.w;
                }
            }
        }

        // reduce: 4x DPP row_ror rotate-accumulate (VALU; collapses each
        // 16-lane row) + 2 cross-group shuffle levels. DS ops 24 -> 8 per
        // wave: the LDS pipe (also draining 64 ds_read_b128/block for the
        // dot) was the block-serialized resource.
#pragma unroll
        for (int r = 0; r < 4; ++r) {
            float v = acc[r];
            DPP_ROR_ACC(v, 0x121);   // row_ror:1
            DPP_ROR_ACC(v, 0x122);   // row_ror:2
            DPP_ROR_ACC(v, 0x124);   // row_ror:4
            DPP_ROR_ACC(v, 0x128);   // row_ror:8
            v += __shfl_xor(v, 16, 64);
            v += __shfl_xor(v, 32, 64);
            acc[r] = v;
        }

        if (L < 4) {
            float a = acc[L] + xp_cur + bh_l;
            a = fminf(fmaxf(a, -15.f), 15.f);
            const float e = __expf(2.f * a);
            const float hval = (e - 1.f) / (e + 1.f);
            const unsigned long long tagged =
                ((unsigned long long)(unsigned)t << 32) |
                (unsigned long long)__float_as_uint(hval);
            __hip_atomic_store(&hbuf[(t & 1) * HID + row], tagged,
                               __ATOMIC_RELAXED, __HIP_MEMORY_SCOPE_AGENT);
            prev_h = hval;
        }
        xp_cur = xp_next;
    }

    if (L < 4) {
        out[(size_t)(SEQ - 1) * HID + row] = prev_h;   // last step's output
        out[(size_t)SEQ * HID + row]       = prev_h;   // h_n
    }
}

// ---------------------------------------------------------------------------
extern "C" void kernel_launch(void* const* d_in, const int* in_sizes, int n_in,
                              void* d_out, int out_size, void* d_ws, size_t ws_size,
                              hipStream_t stream) {
    const float* x  = (const float*)d_in[0];   // [8192,2048] f32
    const float* Wi = (const float*)d_in[1];   // [2048,2048] f32
    const float* bi = (const float*)d_in[2];   // [2048] f32
    const float* Wh = (const float*)d_in[3];   // [2048,2048] f32
    const float* bh = (const float*)d_in[4];   // [2048] f32
    float* out      = (float*)d_out;           // outputs ++ h_n

    // ws: xp f32 [SEQ*HID] (64 MB) | hbuf u64 [2*HID] (32 KB)
    float* xp = (float*)d_ws;
    unsigned long long* hbuf = (unsigned long long*)(xp + (size_t)SEQ * HID);

    xproj_gemm<<<dim3(HID / 64, SEQ / 64), 256, 0, stream>>>(x, Wi, bi, xp);
    rnn_scan<<<NBLK, 512, 0, stream>>>(Wh, bh, xp, hbuf, out);
}